// Round 5
// baseline (398.231 us; speedup 1.0000x reference)
//
#include <hip/hip_runtime.h>
#include <hip/hip_bf16.h>

#define N_NODES 50000
#define N_EDGES 800000
#define N_GRAPHS 512
#define EMB 64
#define HID 128

// -------------------------------------------- embed gather + degree histogram
// N_NODES*16 == N_EDGES == 800000: one grid does both.
__global__ void k_embed_hist(const int* __restrict__ x, const float* __restrict__ emb,
                             const int* __restrict__ ei, float* __restrict__ h0,
                             int* __restrict__ deg) {
    int t = blockIdx.x * 256 + threadIdx.x;
    if (t >= N_EDGES) return;
    int n = t >> 4, c4 = t & 15;
    const float4* e4 = (const float4*)emb;
    ((float4*)h0)[(size_t)n * 16 + c4] = e4[(size_t)x[n] * 16 + c4];
    atomicAdd(&deg[ei[N_EDGES + t]], 1);
}

// ---------------------------------------------------------------- 3-phase scan
__global__ void k_scanA(const int* __restrict__ deg, int* __restrict__ rowptr,
                        int* __restrict__ bsums) {
    __shared__ int s[256];
    int t = threadIdx.x, i = blockIdx.x * 256 + t;
    int v = (i < N_NODES) ? deg[i] : 0;
    s[t] = v; __syncthreads();
    int xv = v;
    for (int off = 1; off < 256; off <<= 1) {
        int y = (t >= off) ? s[t - off] : 0;
        __syncthreads();
        xv += y; s[t] = xv;
        __syncthreads();
    }
    if (i < N_NODES) rowptr[i] = xv - v;
    if (t == 255) bsums[blockIdx.x] = xv;
}

__global__ void k_scanB(int* __restrict__ bsums, int nb) {
    __shared__ int s[256];
    int t = threadIdx.x;
    int v = (t < nb) ? bsums[t] : 0;
    s[t] = v; __syncthreads();
    int xv = v;
    for (int off = 1; off < 256; off <<= 1) {
        int y = (t >= off) ? s[t - off] : 0;
        __syncthreads();
        xv += y; s[t] = xv;
        __syncthreads();
    }
    if (t < nb) bsums[t] = xv - v;
}

__global__ void k_scanC(int* __restrict__ rowptr, int* __restrict__ wp,
                        const int* __restrict__ bsums) {
    int i = blockIdx.x * 256 + threadIdx.x;
    if (i < N_NODES) {
        int v = rowptr[i] + bsums[blockIdx.x];
        rowptr[i] = v;
        wp[i] = v;
    }
    if (i == 0) rowptr[N_NODES] = N_EDGES;
}

// ---------------------------------------------------------------- edge scatter
__global__ void k_scatter(const int* __restrict__ ei, int* __restrict__ wp,
                          int* __restrict__ nbr) {
    int e = blockIdx.x * 256 + threadIdx.x;
    if (e >= N_EDGES) return;
    int s = ei[e], d = ei[N_EDGES + e];
    int pos = atomicAdd(&wp[d], 1);
    nbr[pos] = s;
}

// ------------------------------------------------------------ fused SAGE layer
// out = relu(bias + h@w_r + mean@w_l), one kernel:
//   phase 1: stage h tile (64 nodes x K) -> LDS, GEMM pass 1 (w_r)
//   phase 2: gather neighbor means directly INTO the LDS tile, GEMM pass 2 (w_l)
// block = 512 thr = 8 waves; wave w -> out cols [16w,16w+16); lane -> node.
// Weights read as uniform s_loads. LDS stride K+2 (2-way read alias = free).
template <int K>
__global__ __launch_bounds__(512) void k_fused_layer(
    const float* __restrict__ hin, const int* __restrict__ rowptr,
    const int* __restrict__ nbr, const float* __restrict__ w_r,
    const float* __restrict__ w_l, const float* __restrict__ bias,
    float* __restrict__ out) {
    constexpr int LS = K + 2;
    constexpr int C4 = K / 4;                 // float4 per row
    __shared__ float ls[64 * LS];
    int base = blockIdx.x * 64;
    int t = threadIdx.x;
    int lane = t & 63;
    int wid = __builtin_amdgcn_readfirstlane(t >> 6);   // 0..7
    int j0 = wid * 16;
    int node = base + lane;
    bool valid = node < N_NODES;

    float acc[16];
    #pragma unroll
    for (int j = 0; j < 16; j++) acc[j] = bias[j0 + j];

    const float* lrow = &ls[lane * LS];
    const float4* h4 = (const float4*)hin;

    // ---- phase 1: stage self tile (coalesced float4), GEMM vs w_r
    for (int idx = t; idx < 64 * C4; idx += 512) {
        int r = idx / C4, c4 = idx % C4;
        float4 v = (base + r < N_NODES) ? h4[(size_t)(base + r) * C4 + c4]
                                        : make_float4(0.f, 0.f, 0.f, 0.f);
        float* dp = &ls[r * LS + c4 * 4];
        dp[0] = v.x; dp[1] = v.y; dp[2] = v.z; dp[3] = v.w;
    }
    __syncthreads();
    #pragma unroll 4
    for (int k = 0; k < K; k++) {
        float hv = lrow[k];
        const float* wk = &w_r[(size_t)k * 128 + j0];
        #pragma unroll
        for (int j = 0; j < 16; j++) acc[j] = fmaf(hv, wk[j], acc[j]);
    }
    __syncthreads();                          // tile free for re-use

    // ---- phase 2: gather neighbor means into the tile
    // wave handles 8 nodes; row = C4 lanes of float4 (16 for K=64, 32 for K=128)
    {
        constexpr int RPW = 64 / C4;          // rows gathered in parallel per wave
        int sub = lane / C4;                  // row slot within wave
        int c   = lane % C4;                  // float4 column
        #pragma unroll
        for (int it = 0; it < 8 / RPW; ++it) {
            int row = wid * 8 + it * RPW + sub;
            int n = base + row;
            float4 a0 = {0,0,0,0}, a1 = {0,0,0,0}, a2 = {0,0,0,0}, a3 = {0,0,0,0};
            float inv = 0.0f;
            if (n < N_NODES) {
                int r0 = rowptr[n], r1 = rowptr[n + 1];
                inv = 1.0f / (float)max(r1 - r0, 1);
                int i = r0;
                for (; i + 3 < r1; i += 4) {
                    int s0 = nbr[i], s1 = nbr[i + 1], s2 = nbr[i + 2], s3 = nbr[i + 3];
                    float4 v0 = h4[(size_t)s0 * C4 + c];
                    float4 v1 = h4[(size_t)s1 * C4 + c];
                    float4 v2 = h4[(size_t)s2 * C4 + c];
                    float4 v3 = h4[(size_t)s3 * C4 + c];
                    a0.x += v0.x; a0.y += v0.y; a0.z += v0.z; a0.w += v0.w;
                    a1.x += v1.x; a1.y += v1.y; a1.z += v1.z; a1.w += v1.w;
                    a2.x += v2.x; a2.y += v2.y; a2.z += v2.z; a2.w += v2.w;
                    a3.x += v3.x; a3.y += v3.y; a3.z += v3.z; a3.w += v3.w;
                }
                for (; i < r1; ++i) {
                    float4 v = h4[(size_t)nbr[i] * C4 + c];
                    a0.x += v.x; a0.y += v.y; a0.z += v.z; a0.w += v.w;
                }
            }
            float* dp = &ls[row * LS + c * 4];
            dp[0] = ((a0.x + a1.x) + (a2.x + a3.x)) * inv;
            dp[1] = ((a0.y + a1.y) + (a2.y + a3.y)) * inv;
            dp[2] = ((a0.z + a1.z) + (a2.z + a3.z)) * inv;
            dp[3] = ((a0.w + a1.w) + (a2.w + a3.w)) * inv;
        }
    }
    __syncthreads();

    // ---- GEMM pass 2 vs w_l
    #pragma unroll 4
    for (int k = 0; k < K; k++) {
        float hv = lrow[k];
        const float* wk = &w_l[(size_t)k * 128 + j0];
        #pragma unroll
        for (int j = 0; j < 16; j++) acc[j] = fmaf(hv, wk[j], acc[j]);
    }

    if (!valid) return;
    float4* o4 = (float4*)out;
    #pragma unroll
    for (int jj = 0; jj < 4; jj++) {
        float4 v;
        v.x = fmaxf(acc[jj * 4 + 0], 0.f);
        v.y = fmaxf(acc[jj * 4 + 1], 0.f);
        v.z = fmaxf(acc[jj * 4 + 2], 0.f);
        v.w = fmaxf(acc[jj * 4 + 3], 0.f);
        o4[(size_t)node * 32 + wid * 4 + jj] = v;
    }
}

// ---------------------------------------------------------------- pool + head
__global__ void k_pool_head(const float* __restrict__ h2, const int* __restrict__ batch,
                            const float* __restrict__ w_out, const float* __restrict__ b_out,
                            float* __restrict__ out) {
    int g = blockIdx.x;
    int lo = 0, hi = N_NODES;
    while (lo < hi) { int mid = (lo + hi) >> 1; if (batch[mid] < g) lo = mid + 1; else hi = mid; }
    int s = lo;
    lo = s; hi = N_NODES;
    while (lo < hi) { int mid = (lo + hi) >> 1; if (batch[mid] < g + 1) lo = mid + 1; else hi = mid; }
    int e = lo;

    int f = threadIdx.x & 127, half = threadIdx.x >> 7;
    float acc = 0.0f;
    for (int r = s + half; r < e; r += 2) acc += h2[(size_t)r * 128 + f];
    __shared__ float tmp[256];
    tmp[threadIdx.x] = acc;
    __syncthreads();
    if (half == 0) {
        float p = (tmp[f] + tmp[f + 128]) / (float)max(e - s, 1);
        tmp[f]       = p * w_out[f * 2 + 0];
        tmp[f + 128] = p * w_out[f * 2 + 1];
    }
    __syncthreads();
    for (int str = 64; str > 0; str >>= 1) {
        if (threadIdx.x < str) {
            tmp[threadIdx.x] += tmp[threadIdx.x + str];
            tmp[threadIdx.x + 128] += tmp[threadIdx.x + 128 + str];
        }
        __syncthreads();
    }
    if (threadIdx.x == 0) {
        out[(size_t)g * 2 + 0] = tmp[0] + b_out[0];
        out[(size_t)g * 2 + 1] = tmp[128] + b_out[1];
    }
}

// ---------------------------------------------------------------- launch
extern "C" void kernel_launch(void* const* d_in, const int* in_sizes, int n_in,
                              void* d_out, int out_size, void* d_ws, size_t ws_size,
                              hipStream_t stream) {
    const int*   x      = (const int*)d_in[0];
    const int*   ei     = (const int*)d_in[1];
    const int*   batch  = (const int*)d_in[2];
    const float* emb    = (const float*)d_in[3];
    const float* w1_l   = (const float*)d_in[4];
    const float* b1     = (const float*)d_in[5];
    const float* w1_r   = (const float*)d_in[6];
    const float* w2_l   = (const float*)d_in[7];
    const float* b2     = (const float*)d_in[8];
    const float* w2_r   = (const float*)d_in[9];
    const float* w_out  = (const float*)d_in[10];
    const float* b_out  = (const float*)d_in[11];
    float* out = (float*)d_out;

    // workspace layout (floats)
    float* F = (float*)d_ws;
    float* h0    = F;                                 // N*64
    float* h1    = h0 + (size_t)N_NODES * 64;         // N*128
    float* h2    = h1 + (size_t)N_NODES * 128;        // N*128
    int*   deg   = (int*)(h2 + (size_t)N_NODES * 128);
    int*   rowptr= deg + N_NODES;                     // N+1
    int*   wp    = rowptr + N_NODES + 1;              // N
    int*   nbr   = wp + N_NODES;                      // E
    int*   bsums = nbr + N_EDGES;                     // 256

    const int NB = (N_NODES + 255) / 256;             // 196

    hipMemsetAsync(deg, 0, (size_t)N_NODES * sizeof(int), stream);

    k_embed_hist<<<(N_EDGES + 255) / 256, 256, 0, stream>>>(x, emb, ei, h0, deg);
    k_scanA<<<NB, 256, 0, stream>>>(deg, rowptr, bsums);
    k_scanB<<<1, 256, 0, stream>>>(bsums, NB);
    k_scanC<<<NB, 256, 0, stream>>>(rowptr, wp, bsums);
    k_scatter<<<(N_EDGES + 255) / 256, 256, 0, stream>>>(ei, wp, nbr);

    // fused layers: agg + both GEMM passes in one kernel each
    k_fused_layer<64><<<(N_NODES + 63) / 64, 512, 0, stream>>>(
        h0, rowptr, nbr, w1_r, w1_l, b1, h1);
    k_fused_layer<128><<<(N_NODES + 63) / 64, 512, 0, stream>>>(
        h1, rowptr, nbr, w2_r, w2_l, b2, h2);

    // pool + head
    k_pool_head<<<N_GRAPHS, 256, 0, stream>>>(h2, batch, w_out, b_out, out);

    (void)in_sizes; (void)n_in; (void)out_size; (void)ws_size;
}